// Round 11
// baseline (348.429 us; speedup 1.0000x reference)
//
#include <hip/hip_runtime.h>
#include <math.h>

#define N_KEYS    8192
#define DIM       1024
#define BQ        64
#define TOPK      4
#define HD        512
#define KSPLIT    4
#define KSLICE    (DIM / KSPLIT)     // 256 dims per block
#define NBLK      16                 // keys per block
#define NBLOCKS_K (N_KEYS / NBLK)    // 512 key tiles
#define NB_TOTAL  (NBLOCKS_K * KSPLIT)  // 2048 blocks
#define NMERGE    256                // phase-B merger blocks (64 b x 4 chunks)
#define NFINAL    64                 // phase-C finalizer blocks (one per b)
#define IMAXI     0x7fffffff

typedef _Float16 half8 __attribute__((ext_vector_type(8)));
typedef _Float16 half4 __attribute__((ext_vector_type(4)));
typedef float    f32x4 __attribute__((ext_vector_type(4)));

#define MFMA16(A, B, C) __builtin_amdgcn_mfma_f32_16x16x32_f16(A, B, C, 0, 0, 0)

__device__ __forceinline__ bool better(float av, int ai, float bv, int bi) {
    return (av > bv) || (av == bv && ai < bi);
}

__device__ __forceinline__ void ce(float& av, int& ai, float& bv, int& bi) {
    if (!better(av, ai, bv, bi)) {
        float tv = av; av = bv; bv = tv;
        int   ti = ai; ai = bi; bi = ti;
    }
}

__device__ __forceinline__ void ins4(float v[4], int ix[4], float s, int gi) {
    if (better(s, gi, v[3], ix[3])) {
        v[3] = s; ix[3] = gi;
        #pragma unroll
        for (int p = 3; p > 0; --p) {
            if (better(v[p], ix[p], v[p - 1], ix[p - 1])) {
                float tv = v[p]; v[p] = v[p-1]; v[p-1] = tv;
                int   ti = ix[p]; ix[p] = ix[p-1]; ix[p-1] = ti;
            }
        }
    }
}

__device__ __forceinline__ void merge_shfl(float v[4], int ix[4], int off) {
    float pv[4]; int pi[4];
    #pragma unroll
    for (int r = 0; r < 4; ++r) {
        pv[r] = __shfl_xor(v[r], off);
        pi[r] = __shfl_xor(ix[r], off);
    }
    float nv[4]; int ni[4];
    #pragma unroll
    for (int r = 0; r < 4; ++r) {
        bool ta = better(v[r], ix[r], pv[3 - r], pi[3 - r]);
        nv[r] = ta ? v[r]  : pv[3 - r];
        ni[r] = ta ? ix[r] : pi[3 - r];
    }
    ce(nv[0], ni[0], nv[2], ni[2]);
    ce(nv[1], ni[1], nv[3], ni[3]);
    ce(nv[0], ni[0], nv[1], ni[1]);
    ce(nv[2], ni[2], nv[3], ni[3]);
    #pragma unroll
    for (int r = 0; r < 4; ++r) { v[r] = nv[r]; ix[r] = ni[r]; }
}

// ---------------- prep: eq = exp(q) split into hi/lo f16 ----------------
__global__ __launch_bounds__(256) void prep_q(const float4* __restrict__ q4,
                                              _Float16* __restrict__ eqh,
                                              _Float16* __restrict__ eql) {
    int i = blockIdx.x * 256 + threadIdx.x;
    float4 v = q4[i];
    float e0 = __expf(v.x), e1 = __expf(v.y), e2 = __expf(v.z), e3 = __expf(v.w);
    half4 h, l;
    h[0] = (_Float16)e0; h[1] = (_Float16)e1; h[2] = (_Float16)e2; h[3] = (_Float16)e3;
    l[0] = (_Float16)(e0 - (float)h[0]); l[1] = (_Float16)(e1 - (float)h[1]);
    l[2] = (_Float16)(e2 - (float)h[2]); l[3] = (_Float16)(e3 - (float)h[3]);
    *(half4*)&eqh[i * 4] = h;
    *(half4*)&eql[i * 4] = l;
}

__device__ __forceinline__ void split8(const float4& a, const float4& b,
                                       half8& h, half8& l) {
    float e[8] = {__expf(a.x), __expf(a.y), __expf(a.z), __expf(a.w),
                  __expf(b.x), __expf(b.y), __expf(b.z), __expf(b.w)};
    #pragma unroll
    for (int j = 0; j < 8; ++j) {
        _Float16 hh = (_Float16)e[j];
        h[j] = hh;
        l[j] = (_Float16)(e[j] - (float)hh);
    }
}

// LDS slot index for (dim-group cs, key k), XOR-swizzled (R10: 0 conflicts)
__device__ __forceinline__ int lds_idx(int cs, int k) {
    return cs * 16 + ((k ^ (cs & 15) ^ (cs >> 3)) & 15);
}

// ---------------- mega: scores (phase A) + topk (B) + finalize (C) ------------
// Phase A: exact R10 scores body. Then last-arriver tickets pick 256 merger
// blocks (phase B: per (b,chunk) top-4 over 2048 keys) and 64 finalizers
// (phase C: merge 4 lists, softmax, gather). No co-residency assumptions.
__global__ __launch_bounds__(256, 8) void mega_kernel(
        const _Float16* __restrict__ eqh, const _Float16* __restrict__ eql,
        const float* __restrict__ keys,
        const float* __restrict__ theta, const float* __restrict__ mag,
        float* __restrict__ part, float* __restrict__ cv, int* __restrict__ ci,
        int* __restrict__ ctr, float* __restrict__ out) {
    __shared__ _Float16 Bh[NBLK * KSLICE];   // 8 KB
    __shared__ _Float16 Bl[NBLK * KSLICE];   // 8 KB
    __shared__ float sv[4][4];
    __shared__ int   si[4][4];
    __shared__ float fw[4];
    __shared__ int   fi[4];
    __shared__ int   tick;

    const int t = threadIdx.x, lane = t & 63, w = t >> 6, wid = t >> 6;
    const int l15 = lane & 15, l4 = lane >> 4;

    // ================= phase A: partial scores (R10 body) =================
    {
        const int kb = blockIdx.x & (NBLOCKS_K - 1);
        const int sl = blockIdx.x >> 9;
        const int dbase = sl * KSLICE;
        const int i0 = kb * NBLK;

        const int sk  = t >> 5;     // staging key 0..7 (and +8)
        const int scs = t & 31;     // staging dim-group 0..31

        const float* p0 = keys + (size_t)(i0 + sk) * DIM + dbase + scs * 8;
        const float* p1 = keys + (size_t)(i0 + 8 + sk) * DIM + dbase + scs * 8;
        float4 r0a = ((const float4*)p0)[0], r0b = ((const float4*)p0)[1];
        float4 r1a = ((const float4*)p1)[0], r1b = ((const float4*)p1)[1];

        const _Float16* ap_h = eqh + (size_t)(w * 16 + l15) * DIM + dbase + l4 * 8;
        const _Float16* ap_l = eql + (size_t)(w * 16 + l15) * DIM + dbase + l4 * 8;
        half8 Ah[2], Al[2];
        Ah[0] = *(const half8*)(ap_h);
        Al[0] = *(const half8*)(ap_l);

        half8 h0, l0, h1, l1;
        split8(r0a, r0b, h0, l0);
        split8(r1a, r1b, h1, l1);
        *(half8*)&Bh[lds_idx(scs, sk) * 8]     = h0;
        *(half8*)&Bl[lds_idx(scs, sk) * 8]     = l0;
        *(half8*)&Bh[lds_idx(scs, sk + 8) * 8] = h1;
        *(half8*)&Bl[lds_idx(scs, sk + 8) * 8] = l1;
        __syncthreads();

        f32x4 acc0 = {0.f,0.f,0.f,0.f}, acc1 = {0.f,0.f,0.f,0.f}, acc2 = {0.f,0.f,0.f,0.f};

        #pragma unroll
        for (int c = 0; c < 8; ++c) {
            if (c + 1 < 8) {
                Ah[(c + 1) & 1] = *(const half8*)(ap_h + (c + 1) * 32);
                Al[(c + 1) & 1] = *(const half8*)(ap_l + (c + 1) * 32);
            }
            const int cs = c * 4 + l4;
            half8 bh = *(const half8*)&Bh[lds_idx(cs, l15) * 8];
            half8 bl = *(const half8*)&Bl[lds_idx(cs, l15) * 8];
            acc0 = MFMA16(Ah[c & 1], bh, acc0);
            acc1 = MFMA16(Ah[c & 1], bl, acc1);
            acc2 = MFMA16(Al[c & 1], bh, acc2);
        }

        float* pb = part + (size_t)sl * (BQ * N_KEYS);
        #pragma unroll
        for (int r = 0; r < 4; ++r) {
            int q = w * 16 + l4 * 4 + r;
            pb[(size_t)q * N_KEYS + i0 + l15] = acc0[r] + acc1[r] + acc2[r];
        }
    }

    // ---- ticket 1: last NMERGE arrivers become top-k mergers ----
    __threadfence();
    __syncthreads();
    if (t == 0) tick = atomicAdd(&ctr[0], 1);
    __syncthreads();
    const int t1 = tick;
    if (t1 < NB_TOTAL - NMERGE) return;

    if (t == 0) {
        long guard = 0;
        while (__hip_atomic_load(&ctr[0], __ATOMIC_ACQUIRE, __HIP_MEMORY_SCOPE_AGENT)
               < NB_TOTAL && guard < (1L << 28)) { __builtin_amdgcn_s_sleep(2); ++guard; }
    }
    __syncthreads();
    __threadfence();

    // ================= phase B: top-4 per (b, quarter-of-keys) =================
    {
        const int mid   = t1 - (NB_TOTAL - NMERGE);   // 0..255
        const int b     = mid >> 2;
        const int chunk = mid & 3;

        float v[4]  = {-INFINITY, -INFINITY, -INFINITY, -INFINITY};
        int   ix[4] = {IMAXI, IMAXI, IMAXI, IMAXI};

        const float* pb = part + (size_t)b * N_KEYS;
        #pragma unroll
        for (int r = 0; r < 8; ++r) {
            int i = chunk * 2048 + r * 256 + t;
            float s = pb[i]
                    + pb[(size_t)1 * BQ * N_KEYS + i]
                    + pb[(size_t)2 * BQ * N_KEYS + i]
                    + pb[(size_t)3 * BQ * N_KEYS + i];
            ins4(v, ix, s, i);
        }
        merge_shfl(v, ix, 1);  merge_shfl(v, ix, 2);  merge_shfl(v, ix, 4);
        merge_shfl(v, ix, 8);  merge_shfl(v, ix, 16); merge_shfl(v, ix, 32);

        if (lane == 0) {
            #pragma unroll
            for (int r = 0; r < 4; ++r) { sv[wid][r] = v[r]; si[wid][r] = ix[r]; }
        }
        __syncthreads();

        if (wid == 0) {
            float mv[4]; int mi[4];
            if (lane < 4) {
                #pragma unroll
                for (int r = 0; r < 4; ++r) { mv[r] = sv[lane][r]; mi[r] = si[lane][r]; }
            } else {
                #pragma unroll
                for (int r = 0; r < 4; ++r) { mv[r] = -INFINITY; mi[r] = IMAXI; }
            }
            merge_shfl(mv, mi, 1); merge_shfl(mv, mi, 2);
            if (lane == 0) {
                #pragma unroll
                for (int r = 0; r < 4; ++r) {
                    cv[mid * 4 + r] = mv[r];
                    ci[mid * 4 + r] = mi[r];
                }
            }
        }
    }

    // ---- ticket 2: last NFINAL mergers become finalizers ----
    __threadfence();
    __syncthreads();
    if (t == 0) tick = atomicAdd(&ctr[1], 1);
    __syncthreads();
    const int t2 = tick;
    if (t2 < NMERGE - NFINAL) return;

    if (t == 0) {
        long guard = 0;
        while (__hip_atomic_load(&ctr[1], __ATOMIC_ACQUIRE, __HIP_MEMORY_SCOPE_AGENT)
               < NMERGE && guard < (1L << 28)) { __builtin_amdgcn_s_sleep(2); ++guard; }
    }
    __syncthreads();
    __threadfence();

    // ================= phase C: finalize query b = t2 - 192 =================
    {
        const int b = t2 - (NMERGE - NFINAL);   // 0..63

        float v[4]  = {-INFINITY, -INFINITY, -INFINITY, -INFINITY};
        int   ix[4] = {IMAXI, IMAXI, IMAXI, IMAXI};
        if (t < 4) {
            #pragma unroll
            for (int r = 0; r < 4; ++r) {
                v[r]  = cv[(b * 4 + t) * 4 + r];
                ix[r] = ci[(b * 4 + t) * 4 + r];
            }
        }
        if (wid == 0) { merge_shfl(v, ix, 1); merge_shfl(v, ix, 2); }

        if (t == 0) {
            float ssum = v[0] + v[1] + v[2] + v[3];   // positive exp-sums
            #pragma unroll
            for (int r = 0; r < 4; ++r) { fw[r] = v[r] / ssum; fi[r] = ix[r]; }
        }
        __syncthreads();

        const float4* th4 = (const float4*)theta;
        float4* out4 = (float4*)out;
        #pragma unroll
        for (int r = 0; r < 2; ++r) {
            int l = t + r * 256;          // 0..511
            int j = l >> 7, c4 = l & 127;
            out4[((size_t)b * TOPK + j) * (HD / 4) + c4] =
                th4[(size_t)fi[j] * (HD / 4) + c4];
        }
        if (t < TOPK) {
            out[(size_t)BQ * TOPK * HD + b * TOPK + t]             = mag[fi[t]];
            out[(size_t)BQ * TOPK * HD + BQ * TOPK + b * TOPK + t] = fw[t];
        }
    }
}

extern "C" void kernel_launch(void* const* d_in, const int* in_sizes, int n_in,
                              void* d_out, int out_size, void* d_ws, size_t ws_size,
                              hipStream_t stream) {
    const float* q     = (const float*)d_in[0];
    const float* keys  = (const float*)d_in[1];
    const float* theta = (const float*)d_in[2];
    const float* mag   = (const float*)d_in[3];
    float* out = (float*)d_out;

    // ws layout: ctr(256B) | part 8MB | eqh 128KB | eql 128KB | cv 4KB | ci 4KB
    int*      ctr  = (int*)d_ws;
    float*    part = (float*)((char*)d_ws + 256);
    _Float16* eqh  = (_Float16*)(part + (size_t)KSPLIT * BQ * N_KEYS);
    _Float16* eql  = eqh + (size_t)BQ * DIM;
    float*    cv   = (float*)(eql + (size_t)BQ * DIM);
    int*      ci   = (int*)(cv + NMERGE * TOPK);

    hipMemsetAsync(ctr, 0, 256, stream);
    prep_q<<<BQ * DIM / 4 / 256, 256, 0, stream>>>((const float4*)q, eqh, eql);
    mega_kernel<<<NB_TOTAL, 256, 0, stream>>>(eqh, eql, keys, theta, mag,
                                              part, cv, ci, ctr, out);
}